// Round 9
// baseline (115.822 us; speedup 1.0000x reference)
//
#include <hip/hip_runtime.h>
#include <hip/hip_bf16.h>

typedef short bf16x8 __attribute__((ext_vector_type(8)));
typedef float f32x4 __attribute__((ext_vector_type(4)));

constexpr int B_ = 16;
constexpr int L_ = 2048;
constexpr int DM = 512;
constexpr int NS = 64;
constexpr int BL = B_ * L_;          // 32768 rows
constexpr float LN_EPS = 1e-5f;
constexpr float KLN = 2.8853900817779268f;   // 2*log2(e)

constexpr int WARM = 64;
constexpr int RPB  = 128;            // rows per block
constexpr int NBLK = BL / RPB;       // 256

__device__ __forceinline__ unsigned f32bits(float f) {
    union { float f; unsigned u; } v{f}; return v.u;
}
__device__ __forceinline__ float bitsf32(unsigned u) {
    union { unsigned u; float f; } v{u}; return v.f;
}
__device__ __forceinline__ unsigned short f2bf(float f) {   // RNE
    unsigned u = f32bits(f);
    unsigned r = u + 0x7FFF + ((u >> 16) & 1);
    return (unsigned short)(r >> 16);
}

// normalize 8 consecutive-k x values and split into hi/lo bf16 fragments.
__device__ __forceinline__ void norm_split8(float4 u0, float4 u1,
                                            float rstd, float m2,
                                            bf16x8& ah, bf16x8& al) {
    float t[8] = { fmaf(u0.x, rstd, m2), fmaf(u0.y, rstd, m2),
                   fmaf(u0.z, rstd, m2), fmaf(u0.w, rstd, m2),
                   fmaf(u1.x, rstd, m2), fmaf(u1.y, rstd, m2),
                   fmaf(u1.z, rstd, m2), fmaf(u1.w, rstd, m2) };
    unsigned hb[8], lb[8];
    #pragma unroll
    for (int j = 0; j < 8; ++j) {
        unsigned tb = f32bits(t[j]);
        hb[j] = tb & 0xFFFF0000u;
        lb[j] = f32bits(t[j] - bitsf32(hb[j]));
    }
    union { unsigned u[4]; bf16x8 v; } H, L;
    #pragma unroll
    for (int p = 0; p < 4; ++p) {
        H.u[p] = (hb[2*p] >> 16) | hb[2*p+1];
        L.u[p] = (lb[2*p] >> 16) | (lb[2*p+1] & 0xFFFF0000u);
    }
    ah = H.v; al = L.v;
}

// ---- Kernel 0: pack A' = diag(gamma)@A split MFMA-B fragments; C into the
//      swapped-operand interleaved fragment order PC2; c0 = beta@A; gd; bd ----
// PC2 frag g2 = dblk*256 + offs*128 + kt*64 + lane :
//   d = dblk*32 + ((lane&15)>>2)*8 + offs*4 + (lane&3); n = kt*32 + (lane>>4)*8 + j
__global__ __launch_bounds__(256) void k_pack(const float* __restrict__ A,
                                              const float* __restrict__ C,
                                              const float* __restrict__ gamma,
                                              const float* __restrict__ beta,
                                              const float* __restrict__ Dv,
                                              unsigned short* __restrict__ PAh,
                                              unsigned short* __restrict__ PAl,
                                              unsigned short* __restrict__ PC2,
                                              float* __restrict__ c0,
                                              float* __restrict__ gd,
                                              float* __restrict__ bd) {
    const int blk = blockIdx.x;
    const int tid = threadIdx.x;
    if (blk < 32) {
        const int g = blk * 256 + tid;     // 0..8191
        if (g < 4096) {
            const int lane = g & 63, ct = (g >> 6) & 3, k32 = (g >> 8) & 3, kc = g >> 10;
            const int kbase = kc * 128 + k32 * 32 + (lane >> 4) * 8;
            const int col   = ct * 16 + (lane & 15);
            unsigned hb[8], lb[8];
            #pragma unroll
            for (int j = 0; j < 8; ++j) {
                float v = gamma[kbase + j] * A[(size_t)(kbase + j) * NS + col];
                unsigned tb = f32bits(v);
                hb[j] = tb & 0xFFFF0000u;
                lb[j] = f32bits(v - bitsf32(hb[j]));
            }
            uint4 ph, pl;
            ph.x = (hb[0] >> 16) | hb[1]; ph.y = (hb[2] >> 16) | hb[3];
            ph.z = (hb[4] >> 16) | hb[5]; ph.w = (hb[6] >> 16) | hb[7];
            pl.x = (lb[0] >> 16) | (lb[1] & 0xFFFF0000u);
            pl.y = (lb[2] >> 16) | (lb[3] & 0xFFFF0000u);
            pl.z = (lb[4] >> 16) | (lb[5] & 0xFFFF0000u);
            pl.w = (lb[6] >> 16) | (lb[7] & 0xFFFF0000u);
            *reinterpret_cast<uint4*>(PAh + (size_t)g * 8) = ph;
            *reinterpret_cast<uint4*>(PAl + (size_t)g * 8) = pl;
        } else {
            const int g2   = g - 4096;         // 0..4095
            const int lane = g2 & 63;
            const int kt   = (g2 >> 6) & 1;
            const int offs = (g2 >> 7) & 1;
            const int dblk = g2 >> 8;          // 0..15
            const int i    = lane & 15;
            const int d    = dblk * 32 + ((i >> 2) * 8) + offs * 4 + (i & 3);
            const int nb   = kt * 32 + (lane >> 4) * 8;
            unsigned short v[8];
            #pragma unroll
            for (int j = 0; j < 8; ++j) v[j] = f2bf(C[(size_t)d * NS + nb + j]);
            uint4 p;
            p.x = v[0] | ((unsigned)v[1] << 16); p.y = v[2] | ((unsigned)v[3] << 16);
            p.z = v[4] | ((unsigned)v[5] << 16); p.w = v[6] | ((unsigned)v[7] << 16);
            *reinterpret_cast<uint4*>(PC2 + (size_t)g2 * 8) = p;
        }
    } else {
        // block 32: c0[n] = sum_k beta[k]*A[k][n]; gd, bd
        __shared__ float red[256];
        #pragma unroll
        for (int i = 0; i < 2; ++i) {
            int d = tid + 256 * i;
            gd[d] = gamma[d] * Dv[d];
            bd[d] = beta[d] * Dv[d];
        }
        const int n = tid & 63, part = tid >> 6;
        float s = 0.f;
        #pragma unroll 8
        for (int k = part * 128; k < part * 128 + 128; ++k)
            s += beta[k] * A[(size_t)k * NS + n];
        red[tid] = s;
        __syncthreads();
        if (tid < 64)
            c0[tid] = red[tid] + red[tid + 64] + red[tid + 128] + red[tid + 192];
    }
}

// ---- Kernel 1: fully fused LN+gemmA -> flagged scan -> swapped gemmC ----
// 256 blocks x 512 threads, 1 block/CU. Block owns rows [blk*128, +128).
// x lives in registers (xv[32]) from phase 1 through the final epilogue.
__global__ __launch_bounds__(512, 2) void k_mega(const float* __restrict__ x,
                                                 const unsigned short* __restrict__ PAh,
                                                 const unsigned short* __restrict__ PAl,
                                                 const unsigned short* __restrict__ PC2,
                                                 const float* __restrict__ c0,
                                                 const float* __restrict__ gd,
                                                 const float* __restrict__ bd,
                                                 float* __restrict__ Bu,
                                                 unsigned* __restrict__ flags,
                                                 float* __restrict__ out) {
    __shared__ __align__(16) char smem[131072];
    const int tid  = threadIdx.x;
    const int blk  = blockIdx.x;
    const int w    = tid >> 6;
    const int lane = tid & 63;
    const int myrow = 16 * w + (lane & 15);     // local row 0..127
    const int kb    = (lane >> 4) * 8;
    const int r0    = blk * RPB;
    const float* xrow = x + (size_t)(r0 + myrow) * DM;

    // ================= Phase 1: Bu = LN(x) @ A' + c0 =================
    unsigned short* AsH = (unsigned short*)smem;             // 64 KB
    unsigned short* AsL = (unsigned short*)(smem + 65536);   // 64 KB
    {
        const float4* sh = reinterpret_cast<const float4*>(PAh);
        const float4* sl = reinterpret_cast<const float4*>(PAl);
        float4* dh = reinterpret_cast<float4*>(AsH);
        float4* dl = reinterpret_cast<float4*>(AsL);
        #pragma unroll
        for (int i = 0; i < 8; ++i) {
            dh[tid + 512 * i] = sh[tid + 512 * i];
            dl[tid + 512 * i] = sl[tid + 512 * i];
        }
    }

    float4 xv[32];
    #pragma unroll
    for (int kc = 0; kc < 4; ++kc) {
        #pragma unroll
        for (int k32 = 0; k32 < 4; ++k32) {
            xv[kc * 8 + 2 * k32]     = *reinterpret_cast<const float4*>(
                xrow + kc * 128 + k32 * 32 + kb);
            xv[kc * 8 + 2 * k32 + 1] = *reinterpret_cast<const float4*>(
                xrow + kc * 128 + k32 * 32 + kb + 4);
        }
    }

    float s = 0.f, s2 = 0.f;
    #pragma unroll
    for (int i = 0; i < 32; ++i) {
        float4 a = xv[i];
        s  += (a.x + a.y) + (a.z + a.w);
        s2 += a.x*a.x + a.y*a.y + a.z*a.z + a.w*a.w;
    }
    s += __shfl_xor(s, 16); s2 += __shfl_xor(s2, 16);
    s += __shfl_xor(s, 32); s2 += __shfl_xor(s2, 32);
    const float mean = s * (1.0f / DM);
    const float var  = s2 * (1.0f / DM) - mean * mean;
    const float rstd = rsqrtf(var + LN_EPS);
    const float m2   = -mean * rstd;

    __syncthreads();   // A' staged

    {
        f32x4 acc[4] = {};
        const bf16x8* ABh = reinterpret_cast<const bf16x8*>(AsH);
        const bf16x8* ABl = reinterpret_cast<const bf16x8*>(AsL);
        #pragma unroll
        for (int kc = 0; kc < 4; ++kc) {
            #pragma unroll
            for (int k32 = 0; k32 < 4; ++k32) {
                bf16x8 ah, al;
                norm_split8(xv[kc * 8 + 2 * k32], xv[kc * 8 + 2 * k32 + 1], rstd, m2, ah, al);
                #pragma unroll
                for (int ct = 0; ct < 4; ++ct) {
                    const int fi = ((kc * 4 + k32) * 4 + ct) * 64 + lane;
                    bf16x8 bh = ABh[fi];
                    bf16x8 bl = ABl[fi];
                    acc[ct] = __builtin_amdgcn_mfma_f32_16x16x32_bf16(ah, bh, acc[ct], 0, 0, 0);
                    acc[ct] = __builtin_amdgcn_mfma_f32_16x16x32_bf16(ah, bl, acc[ct], 0, 0, 0);
                    acc[ct] = __builtin_amdgcn_mfma_f32_16x16x32_bf16(al, bh, acc[ct], 0, 0, 0);
                }
            }
        }
        // Bu = acc + c0   (D layout: row=(lane>>4)*4+j, col=lane&15)
        const int orow = r0 + 16 * w + (lane >> 4) * 4;
        #pragma unroll
        for (int ct = 0; ct < 4; ++ct) {
            const int n = ct * 16 + (lane & 15);
            const float c0n = c0[n];
            #pragma unroll
            for (int j = 0; j < 4; ++j)
                Bu[(size_t)(orow + j) * NS + n] = acc[ct][j] + c0n;
        }
    }
    __threadfence();         // make Bu device-visible
    __syncthreads();         // whole block's Bu written (+ all LDS reads done)
    if (tid == 0)
        __hip_atomic_store(&flags[blk], 1u, __ATOMIC_RELEASE, __HIP_MEMORY_SCOPE_AGENT);

    // ================= Phase 2: scan (wave 0) =================
    // Hs: 128 rows x 64 n bf16, XOR-swizzled, smem[0..16K)
    const int l0 = (blk & 15) * RPB;
    const int bb = blk >> 4;
    if (w == 0) {
        if ((blk & 15) != 0) {
            while (__hip_atomic_load(&flags[blk - 1], __ATOMIC_ACQUIRE,
                                     __HIP_MEMORY_SCOPE_AGENT) == 0u)
                __builtin_amdgcn_s_sleep(2);
        }
        constexpr int G = 16;
        const int n     = lane;
        const int start = (l0 == 0) ? 0 : (l0 - WARM);
        const int skip  = l0 - start;             // 0 or 64
        const int nGrp  = (RPB + skip) / G;       // 8 or 12
        const float* bp = Bu + ((size_t)bb * L_ + start) * NS + n;
        char* hbase = smem;

        float bufA[G], bufB[G];
        #pragma unroll
        for (int j = 0; j < G; ++j) bufA[j] = KLN * bp[(size_t)j * NS];
        float hv = 0.0f;
        int g = 0;
        for (;;) {
            {
                if (g + 1 < nGrp) {
                    const int base = (g + 1) * G;
                    #pragma unroll
                    for (int j = 0; j < G; ++j)
                        bufB[j] = KLN * bp[(size_t)(base + j) * NS];
                }
                const int lbase = g * G - skip;
                const bool doStore = lbase >= 0;
                #pragma unroll
                for (int j = 0; j < G; ++j) {
                    float t = fmaf(hv, KLN, bufA[j]);
                    float e = __builtin_amdgcn_exp2f(t);
                    float rr = __builtin_amdgcn_rcpf(e + 1.0f);
                    hv = fmaf(-2.0f, rr, 1.0f);
                    if (doStore) {
                        const int lr = lbase + j;
                        *reinterpret_cast<unsigned short*>(
                            hbase + lr * 128 + ((2 * n) ^ ((lr & 7) << 4))) = f2bf(hv);
                    }
                }
            }
            if (++g == nGrp) break;
            {
                if (g + 1 < nGrp) {
                    const int base = (g + 1) * G;
                    #pragma unroll
                    for (int j = 0; j < G; ++j)
                        bufA[j] = KLN * bp[(size_t)(base + j) * NS];
                }
                const int lbase = g * G - skip;
                const bool doStore = lbase >= 0;
                #pragma unroll
                for (int j = 0; j < G; ++j) {
                    float t = fmaf(hv, KLN, bufB[j]);
                    float e = __builtin_amdgcn_exp2f(t);
                    float rr = __builtin_amdgcn_rcpf(e + 1.0f);
                    hv = fmaf(-2.0f, rr, 1.0f);
                    if (doStore) {
                        const int lr = lbase + j;
                        *reinterpret_cast<unsigned short*>(
                            hbase + lr * 128 + ((2 * n) ^ ((lr & 7) << 4))) = f2bf(hv);
                    }
                }
            }
            if (++g == nGrp) break;
        }
    } else {
        // waves 1-7: stage gd/bd into LDS at smem[16K..20K)
        float* GdS = (float*)(smem + 16384);
        const int t2 = tid - 64;                 // 0..447
        if (t2 < 256)
            reinterpret_cast<float4*>(GdS)[t2] =
                (t2 < 128) ? reinterpret_cast<const float4*>(gd)[t2]
                           : reinterpret_cast<const float4*>(bd)[t2 - 128];
    }
    __syncthreads();

    // ================= Phase 3: out = h @ C^T + z*gd + bd + x =================
    // Swapped operands: acc = mfma(C_frag, h_frag) -> D[d_local][r]; lane gets
    // (r = myrow, d = dblk*32 + kb + offs*4 + j) == exactly its xv elements.
    const float* GdS = (const float*)(smem + 16384);
    const float* BdS = GdS + DM;

    bf16x8 hfr0, hfr1;
    {
        const int hr = myrow;
        hfr0 = *reinterpret_cast<const bf16x8*>(
            smem + hr * 128 + (((lane >> 4) * 16) ^ ((hr & 7) << 4)));
        hfr1 = *reinterpret_cast<const bf16x8*>(
            smem + hr * 128 + ((64 + (lane >> 4) * 16) ^ ((hr & 7) << 4)));
    }
    float* orp = out + (size_t)(r0 + myrow) * DM;
    #pragma unroll
    for (int dblk = 0; dblk < 16; ++dblk) {
        bf16x8 c00 = *reinterpret_cast<const bf16x8*>(PC2 + ((size_t)dblk * 256 + lane) * 8);
        bf16x8 c01 = *reinterpret_cast<const bf16x8*>(PC2 + ((size_t)dblk * 256 + 64 + lane) * 8);
        bf16x8 c10 = *reinterpret_cast<const bf16x8*>(PC2 + ((size_t)dblk * 256 + 128 + lane) * 8);
        bf16x8 c11 = *reinterpret_cast<const bf16x8*>(PC2 + ((size_t)dblk * 256 + 192 + lane) * 8);
        f32x4 a0 = {}, a1 = {};
        a0 = __builtin_amdgcn_mfma_f32_16x16x32_bf16(c00, hfr0, a0, 0, 0, 0);
        a0 = __builtin_amdgcn_mfma_f32_16x16x32_bf16(c01, hfr1, a0, 0, 0, 0);
        a1 = __builtin_amdgcn_mfma_f32_16x16x32_bf16(c10, hfr0, a1, 0, 0, 0);
        a1 = __builtin_amdgcn_mfma_f32_16x16x32_bf16(c11, hfr1, a1, 0, 0, 0);

        const int kc  = dblk >> 2, k32 = dblk & 3;
        const float4 x0 = xv[kc * 8 + 2 * k32];
        const float4 x1 = xv[kc * 8 + 2 * k32 + 1];
        const int db = dblk * 32 + kb;
        const float4 g0 = *reinterpret_cast<const float4*>(GdS + db);
        const float4 g1 = *reinterpret_cast<const float4*>(GdS + db + 4);
        const float4 d0 = *reinterpret_cast<const float4*>(BdS + db);
        const float4 d1 = *reinterpret_cast<const float4*>(BdS + db + 4);
        float4 o0, o1;
        o0.x = fmaf((x0.x - mean) * rstd, g0.x, a0[0] + d0.x + x0.x);
        o0.y = fmaf((x0.y - mean) * rstd, g0.y, a0[1] + d0.y + x0.y);
        o0.z = fmaf((x0.z - mean) * rstd, g0.z, a0[2] + d0.z + x0.z);
        o0.w = fmaf((x0.w - mean) * rstd, g0.w, a0[3] + d0.w + x0.w);
        o1.x = fmaf((x1.x - mean) * rstd, g1.x, a1[0] + d1.x + x1.x);
        o1.y = fmaf((x1.y - mean) * rstd, g1.y, a1[1] + d1.y + x1.y);
        o1.z = fmaf((x1.z - mean) * rstd, g1.z, a1[2] + d1.z + x1.z);
        o1.w = fmaf((x1.w - mean) * rstd, g1.w, a1[3] + d1.w + x1.w);
        *reinterpret_cast<float4*>(orp + db)     = o0;
        *reinterpret_cast<float4*>(orp + db + 4) = o1;
    }
}

extern "C" void kernel_launch(void* const* d_in, const int* in_sizes, int n_in,
                              void* d_out, int out_size, void* d_ws, size_t ws_size,
                              hipStream_t stream) {
    const float* x     = (const float*)d_in[0];
    const float* A     = (const float*)d_in[1];
    const float* C     = (const float*)d_in[2];
    const float* Dv    = (const float*)d_in[3];
    const float* gamma = (const float*)d_in[4];
    const float* beta  = (const float*)d_in[5];
    float* out = (float*)d_out;

    char* p = (char*)d_ws;
    float* Bu           = (float*)p;                 p += (size_t)BL * NS * 4;   // 8 MB
    unsigned short* PAh = (unsigned short*)p;        p += (size_t)DM * NS * 2;   // 64 KB
    unsigned short* PAl = (unsigned short*)p;        p += (size_t)DM * NS * 2;
    unsigned short* PC2 = (unsigned short*)p;        p += (size_t)DM * NS * 2;
    float* c0           = (float*)p;                 p += 256;
    float* gd           = (float*)p;                 p += (size_t)DM * 4;
    float* bd           = (float*)p;                 p += (size_t)DM * 4;
    unsigned* flags     = (unsigned*)p;

    k_pack<<<33, 256, 0, stream>>>(A, C, gamma, beta, Dv, PAh, PAl, PC2, c0, gd, bd);
    hipMemsetAsync(flags, 0, NBLK * sizeof(unsigned), stream);
    k_mega<<<NBLK, 512, 0, stream>>>(x, PAh, PAl, PC2, c0, gd, bd, Bu, flags, out);
}

// Round 10
// 73.060 us; speedup vs baseline: 1.5853x; 1.5853x over previous
//
#include <hip/hip_runtime.h>
#include <hip/hip_bf16.h>

typedef short bf16x8 __attribute__((ext_vector_type(8)));
typedef float f32x4 __attribute__((ext_vector_type(4)));

constexpr int B_ = 16;
constexpr int L_ = 2048;
constexpr int DM = 512;
constexpr int NS = 64;
constexpr int BL = B_ * L_;          // 32768 rows
constexpr float LN_EPS = 1e-5f;
constexpr float KLN = 2.8853900817779268f;   // 2*log2(e)

constexpr int SEGS = 32;
constexpr int LSEG = L_ / SEGS;      // 64
constexpr int WARM = 64;

__device__ __forceinline__ unsigned f32bits(float f) {
    union { float f; unsigned u; } v{f}; return v.u;
}
__device__ __forceinline__ float bitsf32(unsigned u) {
    union { unsigned u; float f; } v{u}; return v.f;
}
__device__ __forceinline__ unsigned short f2bf(float f) {   // RNE
    unsigned u = f32bits(f);
    unsigned r = u + 0x7FFF + ((u >> 16) & 1);
    return (unsigned short)(r >> 16);
}

// normalize 8 consecutive-k x values and split into hi/lo bf16 fragments.
__device__ __forceinline__ void norm_split8(float4 u0, float4 u1,
                                            float rstd, float m2,
                                            bf16x8& ah, bf16x8& al) {
    float t[8] = { fmaf(u0.x, rstd, m2), fmaf(u0.y, rstd, m2),
                   fmaf(u0.z, rstd, m2), fmaf(u0.w, rstd, m2),
                   fmaf(u1.x, rstd, m2), fmaf(u1.y, rstd, m2),
                   fmaf(u1.z, rstd, m2), fmaf(u1.w, rstd, m2) };
    unsigned hb[8], lb[8];
    #pragma unroll
    for (int j = 0; j < 8; ++j) {
        unsigned tb = f32bits(t[j]);
        hb[j] = tb & 0xFFFF0000u;
        lb[j] = f32bits(t[j] - bitsf32(hb[j]));
    }
    union { unsigned u[4]; bf16x8 v; } H, L;
    #pragma unroll
    for (int p = 0; p < 4; ++p) {
        H.u[p] = (hb[2*p] >> 16) | hb[2*p+1];
        L.u[p] = (lb[2*p] >> 16) | (lb[2*p+1] & 0xFFFF0000u);
    }
    ah = H.v; al = L.v;
}

// ---- Kernel 0: pack A' = diag(gamma)@A into split MFMA-B fragments; C into
//      plain bf16 [d][n]; c0 = beta@A; gd = gamma*D; bd = beta*D. ----
__global__ __launch_bounds__(256) void k_pack(const float* __restrict__ A,
                                              const float* __restrict__ C,
                                              const float* __restrict__ gamma,
                                              const float* __restrict__ beta,
                                              const float* __restrict__ Dv,
                                              unsigned short* __restrict__ PAh,
                                              unsigned short* __restrict__ PAl,
                                              unsigned short* __restrict__ PC,
                                              float* __restrict__ c0,
                                              float* __restrict__ gd,
                                              float* __restrict__ bd) {
    const int blk = blockIdx.x;
    const int tid = threadIdx.x;
    if (blk < 32) {
        const int g = blk * 256 + tid;     // 0..8191
        if (g < 4096) {
            const int lane = g & 63, ct = (g >> 6) & 3, k32 = (g >> 8) & 3, kc = g >> 10;
            const int kbase = kc * 128 + k32 * 32 + (lane >> 4) * 8;
            const int col   = ct * 16 + (lane & 15);
            unsigned hb[8], lb[8];
            #pragma unroll
            for (int j = 0; j < 8; ++j) {
                float v = gamma[kbase + j] * A[(size_t)(kbase + j) * NS + col];
                unsigned tb = f32bits(v);
                hb[j] = tb & 0xFFFF0000u;
                lb[j] = f32bits(v - bitsf32(hb[j]));
            }
            uint4 ph, pl;
            ph.x = (hb[0] >> 16) | hb[1]; ph.y = (hb[2] >> 16) | hb[3];
            ph.z = (hb[4] >> 16) | hb[5]; ph.w = (hb[6] >> 16) | hb[7];
            pl.x = (lb[0] >> 16) | (lb[1] & 0xFFFF0000u);
            pl.y = (lb[2] >> 16) | (lb[3] & 0xFFFF0000u);
            pl.z = (lb[4] >> 16) | (lb[5] & 0xFFFF0000u);
            pl.w = (lb[6] >> 16) | (lb[7] & 0xFFFF0000u);
            *reinterpret_cast<uint4*>(PAh + (size_t)g * 8) = ph;
            *reinterpret_cast<uint4*>(PAl + (size_t)g * 8) = pl;
        } else {
            const int g2 = g - 4096;       // 0..4095; 8 elems each, plain layout
            unsigned short v[8];
            #pragma unroll
            for (int j = 0; j < 8; ++j) v[j] = f2bf(C[(size_t)g2 * 8 + j]);
            uint4 p;
            p.x = v[0] | ((unsigned)v[1] << 16); p.y = v[2] | ((unsigned)v[3] << 16);
            p.z = v[4] | ((unsigned)v[5] << 16); p.w = v[6] | ((unsigned)v[7] << 16);
            *reinterpret_cast<uint4*>(PC + (size_t)g2 * 8) = p;
        }
    } else {
        // block 32: c0[n] = sum_k beta[k]*A[k][n]; gd, bd
        __shared__ float red[256];
        #pragma unroll
        for (int i = 0; i < 2; ++i) {
            int d = tid + 256 * i;
            gd[d] = gamma[d] * Dv[d];
            bd[d] = beta[d] * Dv[d];
        }
        const int n = tid & 63, part = tid >> 6;
        float s = 0.f;
        #pragma unroll 8
        for (int k = part * 128; k < part * 128 + 128; ++k)
            s += beta[k] * A[(size_t)k * NS + n];
        red[tid] = s;
        __syncthreads();
        if (tid < 64)
            c0[tid] = red[tid] + red[tid + 64] + red[tid + 128] + red[tid + 192];
    }
}

// ---- Kernel 1: Bu = z @ A' + c0 via split-bf16 MFMA; z = (x-mean)*rstd ----
// LDS-FREE: 256 thr = 4 waves, 64 rows/block, grid 512. B-fragments are
// MFMA'd directly from global-loaded VGPRs (PA' is 192 KB, L2-resident,
// shared by all blocks on an XCD). x read twice from L3 (stats + fragments)
// instead of register-residency -> low VGPR -> 4+ blocks/CU TLP hides latency.
// No LDS, no barriers at all.
__global__ __launch_bounds__(256) void k_gemmA(const float* __restrict__ x,
                                               const unsigned short* __restrict__ PAh,
                                               const unsigned short* __restrict__ PAl,
                                               const float* __restrict__ c0,
                                               float* __restrict__ stats,
                                               float* __restrict__ Bu) {
    const int tid  = threadIdx.x;
    const int r0   = blockIdx.x * 64;
    const int w    = tid >> 6;
    const int lane = tid & 63;
    const int myrow = 16 * w + (lane & 15);
    const int kb    = (lane >> 4) * 8;
    const float* xrow = x + (size_t)(r0 + myrow) * DM;

    // Pass A: LN stats (each lane sums its own k-stripe; reduce over the
    // 4 lanes {l, l^16, l^32, l^48} that share a row)
    float s = 0.f, s2 = 0.f;
    #pragma unroll
    for (int kc = 0; kc < 4; ++kc) {
        #pragma unroll
        for (int k32 = 0; k32 < 4; ++k32) {
            float4 a = *reinterpret_cast<const float4*>(xrow + kc * 128 + k32 * 32 + kb);
            float4 b = *reinterpret_cast<const float4*>(xrow + kc * 128 + k32 * 32 + kb + 4);
            s  += (a.x + a.y) + (a.z + a.w) + (b.x + b.y) + (b.z + b.w);
            s2 += a.x*a.x + a.y*a.y + a.z*a.z + a.w*a.w
                + b.x*b.x + b.y*b.y + b.z*b.z + b.w*b.w;
        }
    }
    s += __shfl_xor(s, 16); s2 += __shfl_xor(s2, 16);
    s += __shfl_xor(s, 32); s2 += __shfl_xor(s2, 32);
    const float mean = s * (1.0f / DM);
    const float var  = s2 * (1.0f / DM) - mean * mean;
    const float rstd = rsqrtf(var + LN_EPS);
    const float m2   = -mean * rstd;
    if (lane < 16) {
        stats[2 * (r0 + myrow)]     = mean;
        stats[2 * (r0 + myrow) + 1] = rstd;
    }

    // Pass B: fragments re-read from L1/L2/L3 (same addresses), MFMA with
    // B operands straight from global.
    f32x4 acc[4] = {};
    const bf16x8* ABh = reinterpret_cast<const bf16x8*>(PAh);
    const bf16x8* ABl = reinterpret_cast<const bf16x8*>(PAl);
    #pragma unroll
    for (int kc = 0; kc < 4; ++kc) {
        #pragma unroll
        for (int k32 = 0; k32 < 4; ++k32) {
            float4 u0 = *reinterpret_cast<const float4*>(xrow + kc * 128 + k32 * 32 + kb);
            float4 u1 = *reinterpret_cast<const float4*>(xrow + kc * 128 + k32 * 32 + kb + 4);
            bf16x8 ah, al;
            norm_split8(u0, u1, rstd, m2, ah, al);
            #pragma unroll
            for (int ct = 0; ct < 4; ++ct) {
                const int fi = ((kc * 4 + k32) * 4 + ct) * 64 + lane;
                bf16x8 bh = ABh[fi];
                bf16x8 bl = ABl[fi];
                acc[ct] = __builtin_amdgcn_mfma_f32_16x16x32_bf16(ah, bh, acc[ct], 0, 0, 0);
                acc[ct] = __builtin_amdgcn_mfma_f32_16x16x32_bf16(ah, bl, acc[ct], 0, 0, 0);
                acc[ct] = __builtin_amdgcn_mfma_f32_16x16x32_bf16(al, bh, acc[ct], 0, 0, 0);
            }
        }
    }

    // Epilogue: Bu = acc + c0[n]  (D layout: row=(lane>>4)*4+j, col=lane&15)
    const int orow = r0 + 16 * w + (lane >> 4) * 4;
    #pragma unroll
    for (int ct = 0; ct < 4; ++ct) {
        const int n = ct * 16 + (lane & 15);
        const float c0n = c0[n];
        #pragma unroll
        for (int j = 0; j < 4; ++j)
            Bu[(size_t)(orow + j) * NS + n] = acc[ct][j] + c0n;
    }
}

// ---- Kernel 2: fused scan + gemmC. Grid 512 = 16 b x 32 seg, 512 thr.
// Wave 0: recurrence for the block's 64 live rows (warmup 64) -> h in LDS
// (XOR-swizzled bf16). After one barrier: all 8 waves compute
// out[64 x 512] = h @ C^T + z*gd + bd + x, C-fragments direct from L2 PC.
__global__ __launch_bounds__(512, 4) void k_scanC(const float* __restrict__ x,
                                                  const unsigned short* __restrict__ PC,
                                                  const float* __restrict__ gd,
                                                  const float* __restrict__ bd,
                                                  const float* __restrict__ stats,
                                                  const float* __restrict__ Bu,
                                                  float* __restrict__ out) {
    __shared__ unsigned short Hs[64 * 64];   // 8 KB, rows 128 B, XOR-swizzled
    const int tid = threadIdx.x;
    const int seg = blockIdx.x & (SEGS - 1);
    const int b   = blockIdx.x >> 5;
    const int l0  = seg * LSEG;
    const int rowbase = b * L_ + l0;         // first live row

    if (tid < 64) {
        constexpr int G = 16;
        const int n     = tid;
        const int start = (seg == 0) ? 0 : (l0 - WARM);
        const int skip  = l0 - start;            // 0 or 64
        const int nGrp  = (l0 + LSEG - start) / G;
        const float* bp = Bu + ((size_t)b * L_ + start) * NS + n;
        char* hbase = reinterpret_cast<char*>(Hs);

        float bufA[G], bufB[G];
        #pragma unroll
        for (int j = 0; j < G; ++j) bufA[j] = KLN * bp[(size_t)j * NS];
        float hv = 0.0f;
        int g = 0;
        for (;;) {
            {
                if (g + 1 < nGrp) {
                    const int base = (g + 1) * G;
                    #pragma unroll
                    for (int j = 0; j < G; ++j)
                        bufB[j] = KLN * bp[(size_t)(base + j) * NS];
                }
                const int lbase = g * G - skip;
                const bool doStore = lbase >= 0;
                #pragma unroll
                for (int j = 0; j < G; ++j) {
                    float t = fmaf(hv, KLN, bufA[j]);
                    float e = __builtin_amdgcn_exp2f(t);
                    float rr = __builtin_amdgcn_rcpf(e + 1.0f);
                    hv = fmaf(-2.0f, rr, 1.0f);
                    if (doStore) {
                        const int lr = lbase + j;
                        *reinterpret_cast<unsigned short*>(
                            hbase + lr * 128 + ((2 * n) ^ ((lr & 7) << 4))) = f2bf(hv);
                    }
                }
            }
            if (++g == nGrp) break;
            {
                if (g + 1 < nGrp) {
                    const int base = (g + 1) * G;
                    #pragma unroll
                    for (int j = 0; j < G; ++j)
                        bufA[j] = KLN * bp[(size_t)(base + j) * NS];
                }
                const int lbase = g * G - skip;
                const bool doStore = lbase >= 0;
                #pragma unroll
                for (int j = 0; j < G; ++j) {
                    float t = fmaf(hv, KLN, bufB[j]);
                    float e = __builtin_amdgcn_exp2f(t);
                    float rr = __builtin_amdgcn_rcpf(e + 1.0f);
                    hv = fmaf(-2.0f, rr, 1.0f);
                    if (doStore) {
                        const int lr = lbase + j;
                        *reinterpret_cast<unsigned short*>(
                            hbase + lr * 128 + ((2 * n) ^ ((lr & 7) << 4))) = f2bf(hv);
                    }
                }
            }
            if (++g == nGrp) break;
        }
    }
    __syncthreads();

    // ---- gemmC phase: wave w -> row-tile (w>>1), d-half (w&1)*256 ----
    const int w    = tid >> 6;
    const int lane = tid & 63;
    const int rt   = w >> 1;
    const int dh   = (w & 1) * 256;
    const int arow = rt * 16 + (lane & 15);

    bf16x8 afr[2];
    #pragma unroll
    for (int kt = 0; kt < 2; ++kt) {
        const int byte = arow * 128 + ((kt * 64 + (lane >> 4) * 16) ^ ((arow & 7) << 4));
        afr[kt] = *reinterpret_cast<const bf16x8*>(
            reinterpret_cast<const char*>(Hs) + byte);
    }

    const int rb = rowbase + rt * 16 + (lane >> 4) * 4;
    float mean_[4], rstd_[4];
    #pragma unroll
    for (int j = 0; j < 4; ++j) {
        mean_[j] = stats[2 * (rb + j)];
        rstd_[j] = stats[2 * (rb + j) + 1];
    }

    const int dl = dh + (lane & 15);
    const int n0 = (lane >> 4) * 8;
    #pragma unroll
    for (int ct = 0; ct < 16; ++ct) {
        const int d = dl + ct * 16;
        bf16x8 b0 = *reinterpret_cast<const bf16x8*>(PC + (size_t)d * NS + n0);
        bf16x8 b1 = *reinterpret_cast<const bf16x8*>(PC + (size_t)d * NS + 32 + n0);
        f32x4 a = {};
        a = __builtin_amdgcn_mfma_f32_16x16x32_bf16(afr[0], b0, a, 0, 0, 0);
        a = __builtin_amdgcn_mfma_f32_16x16x32_bf16(afr[1], b1, a, 0, 0, 0);
        const float gdv = gd[d];
        const float bdv = bd[d];
        #pragma unroll
        for (int j = 0; j < 4; ++j) {
            const size_t idx = (size_t)(rb + j) * DM + d;
            const float xv = x[idx];
            const float z  = (xv - mean_[j]) * rstd_[j];
            out[idx] = a[j] + z * gdv + bdv + xv;
        }
    }
}

extern "C" void kernel_launch(void* const* d_in, const int* in_sizes, int n_in,
                              void* d_out, int out_size, void* d_ws, size_t ws_size,
                              hipStream_t stream) {
    const float* x     = (const float*)d_in[0];
    const float* A     = (const float*)d_in[1];
    const float* C     = (const float*)d_in[2];
    const float* Dv    = (const float*)d_in[3];
    const float* gamma = (const float*)d_in[4];
    const float* beta  = (const float*)d_in[5];
    float* out = (float*)d_out;

    char* ws = (char*)d_ws;
    float* Bu           = (float*)(ws);                             // 8 MB
    float* stats        = (float*)(ws + (size_t)BL * NS * 4);       // 256 KB
    char* p = ws + (size_t)BL * NS * 4 + (size_t)BL * 2 * 4;
    unsigned short* PAh = (unsigned short*)p;        p += (size_t)DM * NS * 2;
    unsigned short* PAl = (unsigned short*)p;        p += (size_t)DM * NS * 2;
    unsigned short* PC  = (unsigned short*)p;        p += (size_t)DM * NS * 2;
    float* c0           = (float*)p;                 p += 256;
    float* gd           = (float*)p;                 p += (size_t)DM * 4;
    float* bd           = (float*)p;

    k_pack<<<33, 256, 0, stream>>>(A, C, gamma, beta, Dv, PAh, PAl, PC, c0, gd, bd);
    k_gemmA<<<BL / 64, 256, 0, stream>>>(x, PAh, PAl, c0, stats, Bu);
    k_scanC<<<B_ * SEGS, 512, 0, stream>>>(x, PC, gd, bd, stats, Bu, out);
}

// Round 11
// 68.976 us; speedup vs baseline: 1.6792x; 1.0592x over previous
//
#include <hip/hip_runtime.h>
#include <hip/hip_bf16.h>

typedef short bf16x8 __attribute__((ext_vector_type(8)));
typedef float f32x4 __attribute__((ext_vector_type(4)));

constexpr int B_ = 16;
constexpr int L_ = 2048;
constexpr int DM = 512;
constexpr int NS = 64;
constexpr int BL = B_ * L_;          // 32768 rows
constexpr float LN_EPS = 1e-5f;
constexpr float KLN = 2.8853900817779268f;   // 2*log2(e)

constexpr int SEGS = 32;
constexpr int LSEG = L_ / SEGS;      // 64
constexpr int WARM = 64;

__device__ __forceinline__ unsigned f32bits(float f) {
    union { float f; unsigned u; } v{f}; return v.u;
}
__device__ __forceinline__ float bitsf32(unsigned u) {
    union { unsigned u; float f; } v{u}; return v.f;
}
__device__ __forceinline__ unsigned short f2bf(float f) {   // RNE
    unsigned u = f32bits(f);
    unsigned r = u + 0x7FFF + ((u >> 16) & 1);
    return (unsigned short)(r >> 16);
}

// normalize 8 consecutive-k x values and split into hi/lo bf16 fragments.
__device__ __forceinline__ void norm_split8(float4 u0, float4 u1,
                                            float rstd, float m2,
                                            bf16x8& ah, bf16x8& al) {
    float t[8] = { fmaf(u0.x, rstd, m2), fmaf(u0.y, rstd, m2),
                   fmaf(u0.z, rstd, m2), fmaf(u0.w, rstd, m2),
                   fmaf(u1.x, rstd, m2), fmaf(u1.y, rstd, m2),
                   fmaf(u1.z, rstd, m2), fmaf(u1.w, rstd, m2) };
    unsigned hb[8], lb[8];
    #pragma unroll
    for (int j = 0; j < 8; ++j) {
        unsigned tb = f32bits(t[j]);
        hb[j] = tb & 0xFFFF0000u;
        lb[j] = f32bits(t[j] - bitsf32(hb[j]));
    }
    union { unsigned u[4]; bf16x8 v; } H, L;
    #pragma unroll
    for (int p = 0; p < 4; ++p) {
        H.u[p] = (hb[2*p] >> 16) | hb[2*p+1];
        L.u[p] = (lb[2*p] >> 16) | (lb[2*p+1] & 0xFFFF0000u);
    }
    ah = H.v; al = L.v;
}

// ---- Kernel 0: pack A' = diag(gamma)@A split MFMA-B fragments; C into the
//      swapped-operand interleaved fragment order PC2 (validated in R9);
//      c0 = beta@A; gd = gamma*D; bd = beta*D ----
// PC2 frag g2 = dblk*256 + offs*128 + kt*64 + lane :
//   d = dblk*32 + ((lane&15)>>2)*8 + offs*4 + (lane&3); n = kt*32 + (lane>>4)*8 + j
__global__ __launch_bounds__(256) void k_pack(const float* __restrict__ A,
                                              const float* __restrict__ C,
                                              const float* __restrict__ gamma,
                                              const float* __restrict__ beta,
                                              const float* __restrict__ Dv,
                                              unsigned short* __restrict__ PAh,
                                              unsigned short* __restrict__ PAl,
                                              unsigned short* __restrict__ PC2,
                                              float* __restrict__ c0,
                                              float* __restrict__ gd,
                                              float* __restrict__ bd) {
    const int blk = blockIdx.x;
    const int tid = threadIdx.x;
    if (blk < 32) {
        const int g = blk * 256 + tid;     // 0..8191
        if (g < 4096) {
            const int lane = g & 63, ct = (g >> 6) & 3, k32 = (g >> 8) & 3, kc = g >> 10;
            const int kbase = kc * 128 + k32 * 32 + (lane >> 4) * 8;
            const int col   = ct * 16 + (lane & 15);
            unsigned hb[8], lb[8];
            #pragma unroll
            for (int j = 0; j < 8; ++j) {
                float v = gamma[kbase + j] * A[(size_t)(kbase + j) * NS + col];
                unsigned tb = f32bits(v);
                hb[j] = tb & 0xFFFF0000u;
                lb[j] = f32bits(v - bitsf32(hb[j]));
            }
            uint4 ph, pl;
            ph.x = (hb[0] >> 16) | hb[1]; ph.y = (hb[2] >> 16) | hb[3];
            ph.z = (hb[4] >> 16) | hb[5]; ph.w = (hb[6] >> 16) | hb[7];
            pl.x = (lb[0] >> 16) | (lb[1] & 0xFFFF0000u);
            pl.y = (lb[2] >> 16) | (lb[3] & 0xFFFF0000u);
            pl.z = (lb[4] >> 16) | (lb[5] & 0xFFFF0000u);
            pl.w = (lb[6] >> 16) | (lb[7] & 0xFFFF0000u);
            *reinterpret_cast<uint4*>(PAh + (size_t)g * 8) = ph;
            *reinterpret_cast<uint4*>(PAl + (size_t)g * 8) = pl;
        } else {
            const int g2   = g - 4096;         // 0..4095
            const int lane = g2 & 63;
            const int kt   = (g2 >> 6) & 1;
            const int offs = (g2 >> 7) & 1;
            const int dblk = g2 >> 8;          // 0..15
            const int i    = lane & 15;
            const int d    = dblk * 32 + ((i >> 2) * 8) + offs * 4 + (i & 3);
            const int nb   = kt * 32 + (lane >> 4) * 8;
            unsigned short v[8];
            #pragma unroll
            for (int j = 0; j < 8; ++j) v[j] = f2bf(C[(size_t)d * NS + nb + j]);
            uint4 p;
            p.x = v[0] | ((unsigned)v[1] << 16); p.y = v[2] | ((unsigned)v[3] << 16);
            p.z = v[4] | ((unsigned)v[5] << 16); p.w = v[6] | ((unsigned)v[7] << 16);
            *reinterpret_cast<uint4*>(PC2 + (size_t)g2 * 8) = p;
        }
    } else {
        // block 32: c0[n] = sum_k beta[k]*A[k][n]; gd, bd
        __shared__ float red[256];
        #pragma unroll
        for (int i = 0; i < 2; ++i) {
            int d = tid + 256 * i;
            gd[d] = gamma[d] * Dv[d];
            bd[d] = beta[d] * Dv[d];
        }
        const int n = tid & 63, part = tid >> 6;
        float s = 0.f;
        #pragma unroll 8
        for (int k = part * 128; k < part * 128 + 128; ++k)
            s += beta[k] * A[(size_t)k * NS + n];
        red[tid] = s;
        __syncthreads();
        if (tid < 64)
            c0[tid] = red[tid] + red[tid + 64] + red[tid + 128] + red[tid + 192];
    }
}

// ---- Kernel 1: Bu = z @ A' + c0 via split-bf16 MFMA (LDS-free, R10) ----
__global__ __launch_bounds__(256) void k_gemmA(const float* __restrict__ x,
                                               const unsigned short* __restrict__ PAh,
                                               const unsigned short* __restrict__ PAl,
                                               const float* __restrict__ c0,
                                               float* __restrict__ stats,
                                               float* __restrict__ Bu) {
    const int tid  = threadIdx.x;
    const int r0   = blockIdx.x * 64;
    const int w    = tid >> 6;
    const int lane = tid & 63;
    const int myrow = 16 * w + (lane & 15);
    const int kb    = (lane >> 4) * 8;
    const float* xrow = x + (size_t)(r0 + myrow) * DM;

    float s = 0.f, s2 = 0.f;
    #pragma unroll
    for (int kc = 0; kc < 4; ++kc) {
        #pragma unroll
        for (int k32 = 0; k32 < 4; ++k32) {
            float4 a = *reinterpret_cast<const float4*>(xrow + kc * 128 + k32 * 32 + kb);
            float4 b = *reinterpret_cast<const float4*>(xrow + kc * 128 + k32 * 32 + kb + 4);
            s  += (a.x + a.y) + (a.z + a.w) + (b.x + b.y) + (b.z + b.w);
            s2 += a.x*a.x + a.y*a.y + a.z*a.z + a.w*a.w
                + b.x*b.x + b.y*b.y + b.z*b.z + b.w*b.w;
        }
    }
    s += __shfl_xor(s, 16); s2 += __shfl_xor(s2, 16);
    s += __shfl_xor(s, 32); s2 += __shfl_xor(s2, 32);
    const float mean = s * (1.0f / DM);
    const float var  = s2 * (1.0f / DM) - mean * mean;
    const float rstd = rsqrtf(var + LN_EPS);
    const float m2   = -mean * rstd;
    if (lane < 16) {
        stats[2 * (r0 + myrow)]     = mean;
        stats[2 * (r0 + myrow) + 1] = rstd;
    }

    f32x4 acc[4] = {};
    const bf16x8* ABh = reinterpret_cast<const bf16x8*>(PAh);
    const bf16x8* ABl = reinterpret_cast<const bf16x8*>(PAl);
    #pragma unroll
    for (int kc = 0; kc < 4; ++kc) {
        #pragma unroll
        for (int k32 = 0; k32 < 4; ++k32) {
            float4 u0 = *reinterpret_cast<const float4*>(xrow + kc * 128 + k32 * 32 + kb);
            float4 u1 = *reinterpret_cast<const float4*>(xrow + kc * 128 + k32 * 32 + kb + 4);
            bf16x8 ah, al;
            norm_split8(u0, u1, rstd, m2, ah, al);
            #pragma unroll
            for (int ct = 0; ct < 4; ++ct) {
                const int fi = ((kc * 4 + k32) * 4 + ct) * 64 + lane;
                bf16x8 bh = ABh[fi];
                bf16x8 bl = ABl[fi];
                acc[ct] = __builtin_amdgcn_mfma_f32_16x16x32_bf16(ah, bh, acc[ct], 0, 0, 0);
                acc[ct] = __builtin_amdgcn_mfma_f32_16x16x32_bf16(ah, bl, acc[ct], 0, 0, 0);
                acc[ct] = __builtin_amdgcn_mfma_f32_16x16x32_bf16(al, bh, acc[ct], 0, 0, 0);
            }
        }
    }

    const int orow = r0 + 16 * w + (lane >> 4) * 4;
    #pragma unroll
    for (int ct = 0; ct < 4; ++ct) {
        const int n = ct * 16 + (lane & 15);
        const float c0n = c0[n];
        #pragma unroll
        for (int j = 0; j < 4; ++j)
            Bu[(size_t)(orow + j) * NS + n] = acc[ct][j] + c0n;
    }
}

// ---- Kernel 2: fused scan + swapped-operand gemmC. Grid 512, 512 thr. ----
// Wave 0 scans 64 rows -> h in XOR-swizzled LDS; waves 1-7 stage gd/bd.
// Then each wave computes acc = mfma(C_frag, h_frag): lane owns out elements
// (row = 16*rg+(lane&15), d = dblk*32+(lane>>4)*8+{0..7}) -> x/out accessed
// as 2x float4 per dblk (16 rows x 128 contiguous B per instruction).
__global__ __launch_bounds__(512, 4) void k_scanC(const float* __restrict__ x,
                                                  const unsigned short* __restrict__ PC2,
                                                  const float* __restrict__ gd,
                                                  const float* __restrict__ bd,
                                                  const float* __restrict__ stats,
                                                  const float* __restrict__ Bu,
                                                  float* __restrict__ out) {
    __shared__ __align__(16) char smem[8192 + 4096];   // h (8K) + gd/bd (4K)
    const int tid = threadIdx.x;
    const int seg = blockIdx.x & (SEGS - 1);
    const int b   = blockIdx.x >> 5;
    const int l0  = seg * LSEG;
    const int rowbase = b * L_ + l0;         // first live row

    if (tid < 64) {
        constexpr int G = 16;
        const int n     = tid;
        const int start = (seg == 0) ? 0 : (l0 - WARM);
        const int skip  = l0 - start;            // 0 or 64
        const int nGrp  = (l0 + LSEG - start) / G;
        const float* bp = Bu + ((size_t)b * L_ + start) * NS + n;
        char* hbase = smem;

        float bufA[G], bufB[G];
        #pragma unroll
        for (int j = 0; j < G; ++j) bufA[j] = KLN * bp[(size_t)j * NS];
        float hv = 0.0f;
        int g = 0;
        for (;;) {
            {
                if (g + 1 < nGrp) {
                    const int base = (g + 1) * G;
                    #pragma unroll
                    for (int j = 0; j < G; ++j)
                        bufB[j] = KLN * bp[(size_t)(base + j) * NS];
                }
                const int lbase = g * G - skip;
                const bool doStore = lbase >= 0;
                #pragma unroll
                for (int j = 0; j < G; ++j) {
                    float t = fmaf(hv, KLN, bufA[j]);
                    float e = __builtin_amdgcn_exp2f(t);
                    float rr = __builtin_amdgcn_rcpf(e + 1.0f);
                    hv = fmaf(-2.0f, rr, 1.0f);
                    if (doStore) {
                        const int lr = lbase + j;
                        *reinterpret_cast<unsigned short*>(
                            hbase + lr * 128 + ((2 * n) ^ ((lr & 7) << 4))) = f2bf(hv);
                    }
                }
            }
            if (++g == nGrp) break;
            {
                if (g + 1 < nGrp) {
                    const int base = (g + 1) * G;
                    #pragma unroll
                    for (int j = 0; j < G; ++j)
                        bufA[j] = KLN * bp[(size_t)(base + j) * NS];
                }
                const int lbase = g * G - skip;
                const bool doStore = lbase >= 0;
                #pragma unroll
                for (int j = 0; j < G; ++j) {
                    float t = fmaf(hv, KLN, bufB[j]);
                    float e = __builtin_amdgcn_exp2f(t);
                    float rr = __builtin_amdgcn_rcpf(e + 1.0f);
                    hv = fmaf(-2.0f, rr, 1.0f);
                    if (doStore) {
                        const int lr = lbase + j;
                        *reinterpret_cast<unsigned short*>(
                            hbase + lr * 128 + ((2 * n) ^ ((lr & 7) << 4))) = f2bf(hv);
                    }
                }
            }
            if (++g == nGrp) break;
        }
    } else {
        float* GdS = (float*)(smem + 8192);
        const int t2 = tid - 64;                 // 0..447
        if (t2 < 256)
            reinterpret_cast<float4*>(GdS)[t2] =
                (t2 < 128) ? reinterpret_cast<const float4*>(gd)[t2]
                           : reinterpret_cast<const float4*>(bd)[t2 - 128];
    }
    __syncthreads();

    // ---- swapped gemmC phase: wave w -> row-group (w&3), d-half (w>>2) ----
    const int w    = tid >> 6;
    const int lane = tid & 63;
    const int rg   = w & 3;
    const int half = w >> 2;
    const int hr   = rg * 16 + (lane & 15);     // local row 0..63
    const int kb   = (lane >> 4) * 8;
    const int grow = rowbase + hr;
    const float mean = stats[2 * grow];
    const float rstd = stats[2 * grow + 1];

    bf16x8 hfr0 = *reinterpret_cast<const bf16x8*>(
        smem + hr * 128 + (((lane >> 4) * 16) ^ ((hr & 7) << 4)));
    bf16x8 hfr1 = *reinterpret_cast<const bf16x8*>(
        smem + hr * 128 + ((64 + (lane >> 4) * 16) ^ ((hr & 7) << 4)));

    const float* GdS = (const float*)(smem + 8192);
    const float* BdS = GdS + DM;
    const float* xrp = x + (size_t)grow * DM;
    float* orp = out + (size_t)grow * DM;

    #pragma unroll
    for (int i = 0; i < 8; ++i) {
        const int dblk = half * 8 + i;
        bf16x8 c00 = *reinterpret_cast<const bf16x8*>(PC2 + ((size_t)dblk * 256 + lane) * 8);
        bf16x8 c01 = *reinterpret_cast<const bf16x8*>(PC2 + ((size_t)dblk * 256 + 64 + lane) * 8);
        bf16x8 c10 = *reinterpret_cast<const bf16x8*>(PC2 + ((size_t)dblk * 256 + 128 + lane) * 8);
        bf16x8 c11 = *reinterpret_cast<const bf16x8*>(PC2 + ((size_t)dblk * 256 + 192 + lane) * 8);
        f32x4 a0 = {}, a1 = {};
        a0 = __builtin_amdgcn_mfma_f32_16x16x32_bf16(c00, hfr0, a0, 0, 0, 0);
        a0 = __builtin_amdgcn_mfma_f32_16x16x32_bf16(c01, hfr1, a0, 0, 0, 0);
        a1 = __builtin_amdgcn_mfma_f32_16x16x32_bf16(c10, hfr0, a1, 0, 0, 0);
        a1 = __builtin_amdgcn_mfma_f32_16x16x32_bf16(c11, hfr1, a1, 0, 0, 0);

        const int db = dblk * 32 + kb;
        const float4 x0 = *reinterpret_cast<const float4*>(xrp + db);
        const float4 x1 = *reinterpret_cast<const float4*>(xrp + db + 4);
        const float4 g0 = *reinterpret_cast<const float4*>(GdS + db);
        const float4 g1 = *reinterpret_cast<const float4*>(GdS + db + 4);
        const float4 d0 = *reinterpret_cast<const float4*>(BdS + db);
        const float4 d1 = *reinterpret_cast<const float4*>(BdS + db + 4);
        float4 o0, o1;
        o0.x = fmaf((x0.x - mean) * rstd, g0.x, a0[0] + d0.x + x0.x);
        o0.y = fmaf((x0.y - mean) * rstd, g0.y, a0[1] + d0.y + x0.y);
        o0.z = fmaf((x0.z - mean) * rstd, g0.z, a0[2] + d0.z + x0.z);
        o0.w = fmaf((x0.w - mean) * rstd, g0.w, a0[3] + d0.w + x0.w);
        o1.x = fmaf((x1.x - mean) * rstd, g1.x, a1[0] + d1.x + x1.x);
        o1.y = fmaf((x1.y - mean) * rstd, g1.y, a1[1] + d1.y + x1.y);
        o1.z = fmaf((x1.z - mean) * rstd, g1.z, a1[2] + d1.z + x1.z);
        o1.w = fmaf((x1.w - mean) * rstd, g1.w, a1[3] + d1.w + x1.w);
        *reinterpret_cast<float4*>(orp + db)     = o0;
        *reinterpret_cast<float4*>(orp + db + 4) = o1;
    }
}

extern "C" void kernel_launch(void* const* d_in, const int* in_sizes, int n_in,
                              void* d_out, int out_size, void* d_ws, size_t ws_size,
                              hipStream_t stream) {
    const float* x     = (const float*)d_in[0];
    const float* A     = (const float*)d_in[1];
    const float* C     = (const float*)d_in[2];
    const float* Dv    = (const float*)d_in[3];
    const float* gamma = (const float*)d_in[4];
    const float* beta  = (const float*)d_in[5];
    float* out = (float*)d_out;

    char* ws = (char*)d_ws;
    float* Bu           = (float*)(ws);                             // 8 MB
    float* stats        = (float*)(ws + (size_t)BL * NS * 4);       // 256 KB
    char* p = ws + (size_t)BL * NS * 4 + (size_t)BL * 2 * 4;
    unsigned short* PAh = (unsigned short*)p;        p += (size_t)DM * NS * 2;
    unsigned short* PAl = (unsigned short*)p;        p += (size_t)DM * NS * 2;
    unsigned short* PC2 = (unsigned short*)p;        p += (size_t)DM * NS * 2;
    float* c0           = (float*)p;                 p += 256;
    float* gd           = (float*)p;                 p += (size_t)DM * 4;
    float* bd           = (float*)p;

    k_pack<<<33, 256, 0, stream>>>(A, C, gamma, beta, Dv, PAh, PAl, PC2, c0, gd, bd);
    k_gemmA<<<BL / 64, 256, 0, stream>>>(x, PAh, PAl, c0, stats, Bu);
    k_scanC<<<B_ * SEGS, 512, 0, stream>>>(x, PC2, gd, bd, stats, Bu, out);
}

// Round 12
// 68.875 us; speedup vs baseline: 1.6816x; 1.0015x over previous
//
#include <hip/hip_runtime.h>
#include <hip/hip_bf16.h>

typedef short bf16x8 __attribute__((ext_vector_type(8)));
typedef float f32x4 __attribute__((ext_vector_type(4)));

constexpr int B_ = 16;
constexpr int L_ = 2048;
constexpr int DM = 512;
constexpr int NS = 64;
constexpr int BL = B_ * L_;          // 32768 rows
constexpr float LN_EPS = 1e-5f;
constexpr float KLN = 2.8853900817779268f;   // 2*log2(e)

constexpr int SEGS = 32;
constexpr int LSEG = L_ / SEGS;      // 64
constexpr int WARM = 64;

__device__ __forceinline__ unsigned f32bits(float f) {
    union { float f; unsigned u; } v{f}; return v.u;
}
__device__ __forceinline__ float bitsf32(unsigned u) {
    union { unsigned u; float f; } v{u}; return v.f;
}
__device__ __forceinline__ unsigned short f2bf(float f) {   // RNE
    unsigned u = f32bits(f);
    unsigned r = u + 0x7FFF + ((u >> 16) & 1);
    return (unsigned short)(r >> 16);
}

// normalize 8 consecutive-k x values and split into hi/lo bf16 fragments.
__device__ __forceinline__ void norm_split8(float4 u0, float4 u1,
                                            float rstd, float m2,
                                            bf16x8& ah, bf16x8& al) {
    float t[8] = { fmaf(u0.x, rstd, m2), fmaf(u0.y, rstd, m2),
                   fmaf(u0.z, rstd, m2), fmaf(u0.w, rstd, m2),
                   fmaf(u1.x, rstd, m2), fmaf(u1.y, rstd, m2),
                   fmaf(u1.z, rstd, m2), fmaf(u1.w, rstd, m2) };
    unsigned hb[8], lb[8];
    #pragma unroll
    for (int j = 0; j < 8; ++j) {
        unsigned tb = f32bits(t[j]);
        hb[j] = tb & 0xFFFF0000u;
        lb[j] = f32bits(t[j] - bitsf32(hb[j]));
    }
    union { unsigned u[4]; bf16x8 v; } H, L;
    #pragma unroll
    for (int p = 0; p < 4; ++p) {
        H.u[p] = (hb[2*p] >> 16) | hb[2*p+1];
        L.u[p] = (lb[2*p] >> 16) | (lb[2*p+1] & 0xFFFF0000u);
    }
    ah = H.v; al = L.v;
}

// ---- Kernel 0: pack A' = diag(gamma)@A split MFMA-B fragments; C into the
//      swapped-operand interleaved fragment order PC2 (validated in R9);
//      c0 = beta@A; gd = gamma*D; bd = beta*D ----
// PC2 frag g2 = dblk*256 + offs*128 + kt*64 + lane :
//   d = dblk*32 + ((lane&15)>>2)*8 + offs*4 + (lane&3); n = kt*32 + (lane>>4)*8 + j
__global__ __launch_bounds__(256) void k_pack(const float* __restrict__ A,
                                              const float* __restrict__ C,
                                              const float* __restrict__ gamma,
                                              const float* __restrict__ beta,
                                              const float* __restrict__ Dv,
                                              unsigned short* __restrict__ PAh,
                                              unsigned short* __restrict__ PAl,
                                              unsigned short* __restrict__ PC2,
                                              float* __restrict__ c0,
                                              float* __restrict__ gd,
                                              float* __restrict__ bd) {
    const int blk = blockIdx.x;
    const int tid = threadIdx.x;
    if (blk < 32) {
        const int g = blk * 256 + tid;     // 0..8191
        if (g < 4096) {
            const int lane = g & 63, ct = (g >> 6) & 3, k32 = (g >> 8) & 3, kc = g >> 10;
            const int kbase = kc * 128 + k32 * 32 + (lane >> 4) * 8;
            const int col   = ct * 16 + (lane & 15);
            unsigned hb[8], lb[8];
            #pragma unroll
            for (int j = 0; j < 8; ++j) {
                float v = gamma[kbase + j] * A[(size_t)(kbase + j) * NS + col];
                unsigned tb = f32bits(v);
                hb[j] = tb & 0xFFFF0000u;
                lb[j] = f32bits(v - bitsf32(hb[j]));
            }
            uint4 ph, pl;
            ph.x = (hb[0] >> 16) | hb[1]; ph.y = (hb[2] >> 16) | hb[3];
            ph.z = (hb[4] >> 16) | hb[5]; ph.w = (hb[6] >> 16) | hb[7];
            pl.x = (lb[0] >> 16) | (lb[1] & 0xFFFF0000u);
            pl.y = (lb[2] >> 16) | (lb[3] & 0xFFFF0000u);
            pl.z = (lb[4] >> 16) | (lb[5] & 0xFFFF0000u);
            pl.w = (lb[6] >> 16) | (lb[7] & 0xFFFF0000u);
            *reinterpret_cast<uint4*>(PAh + (size_t)g * 8) = ph;
            *reinterpret_cast<uint4*>(PAl + (size_t)g * 8) = pl;
        } else {
            const int g2   = g - 4096;         // 0..4095
            const int lane = g2 & 63;
            const int kt   = (g2 >> 6) & 1;
            const int offs = (g2 >> 7) & 1;
            const int dblk = g2 >> 8;          // 0..15
            const int i    = lane & 15;
            const int d    = dblk * 32 + ((i >> 2) * 8) + offs * 4 + (i & 3);
            const int nb   = kt * 32 + (lane >> 4) * 8;
            unsigned short v[8];
            #pragma unroll
            for (int j = 0; j < 8; ++j) v[j] = f2bf(C[(size_t)d * NS + nb + j]);
            uint4 p;
            p.x = v[0] | ((unsigned)v[1] << 16); p.y = v[2] | ((unsigned)v[3] << 16);
            p.z = v[4] | ((unsigned)v[5] << 16); p.w = v[6] | ((unsigned)v[7] << 16);
            *reinterpret_cast<uint4*>(PC2 + (size_t)g2 * 8) = p;
        }
    } else {
        // block 32: c0[n] = sum_k beta[k]*A[k][n]; gd, bd
        __shared__ float red[256];
        #pragma unroll
        for (int i = 0; i < 2; ++i) {
            int d = tid + 256 * i;
            gd[d] = gamma[d] * Dv[d];
            bd[d] = beta[d] * Dv[d];
        }
        const int n = tid & 63, part = tid >> 6;
        float s = 0.f;
        #pragma unroll 8
        for (int k = part * 128; k < part * 128 + 128; ++k)
            s += beta[k] * A[(size_t)k * NS + n];
        red[tid] = s;
        __syncthreads();
        if (tid < 64)
            c0[tid] = red[tid] + red[tid + 64] + red[tid + 128] + red[tid + 192];
    }
}

// ---- Kernel 1: Bu = z @ A' + c0 via split-bf16 MFMA (LDS-free, R10) ----
__global__ __launch_bounds__(256) void k_gemmA(const float* __restrict__ x,
                                               const unsigned short* __restrict__ PAh,
                                               const unsigned short* __restrict__ PAl,
                                               const float* __restrict__ c0,
                                               float* __restrict__ stats,
                                               float* __restrict__ Bu) {
    const int tid  = threadIdx.x;
    const int r0   = blockIdx.x * 64;
    const int w    = tid >> 6;
    const int lane = tid & 63;
    const int myrow = 16 * w + (lane & 15);
    const int kb    = (lane >> 4) * 8;
    const float* xrow = x + (size_t)(r0 + myrow) * DM;

    float s = 0.f, s2 = 0.f;
    #pragma unroll
    for (int kc = 0; kc < 4; ++kc) {
        #pragma unroll
        for (int k32 = 0; k32 < 4; ++k32) {
            float4 a = *reinterpret_cast<const float4*>(xrow + kc * 128 + k32 * 32 + kb);
            float4 b = *reinterpret_cast<const float4*>(xrow + kc * 128 + k32 * 32 + kb + 4);
            s  += (a.x + a.y) + (a.z + a.w) + (b.x + b.y) + (b.z + b.w);
            s2 += a.x*a.x + a.y*a.y + a.z*a.z + a.w*a.w
                + b.x*b.x + b.y*b.y + b.z*b.z + b.w*b.w;
        }
    }
    s += __shfl_xor(s, 16); s2 += __shfl_xor(s2, 16);
    s += __shfl_xor(s, 32); s2 += __shfl_xor(s2, 32);
    const float mean = s * (1.0f / DM);
    const float var  = s2 * (1.0f / DM) - mean * mean;
    const float rstd = rsqrtf(var + LN_EPS);
    const float m2   = -mean * rstd;
    if (lane < 16) {
        stats[2 * (r0 + myrow)]     = mean;
        stats[2 * (r0 + myrow) + 1] = rstd;
    }

    f32x4 acc[4] = {};
    const bf16x8* ABh = reinterpret_cast<const bf16x8*>(PAh);
    const bf16x8* ABl = reinterpret_cast<const bf16x8*>(PAl);
    #pragma unroll
    for (int kc = 0; kc < 4; ++kc) {
        #pragma unroll
        for (int k32 = 0; k32 < 4; ++k32) {
            float4 u0 = *reinterpret_cast<const float4*>(xrow + kc * 128 + k32 * 32 + kb);
            float4 u1 = *reinterpret_cast<const float4*>(xrow + kc * 128 + k32 * 32 + kb + 4);
            bf16x8 ah, al;
            norm_split8(u0, u1, rstd, m2, ah, al);
            #pragma unroll
            for (int ct = 0; ct < 4; ++ct) {
                const int fi = ((kc * 4 + k32) * 4 + ct) * 64 + lane;
                bf16x8 bh = ABh[fi];
                bf16x8 bl = ABl[fi];
                acc[ct] = __builtin_amdgcn_mfma_f32_16x16x32_bf16(ah, bh, acc[ct], 0, 0, 0);
                acc[ct] = __builtin_amdgcn_mfma_f32_16x16x32_bf16(ah, bl, acc[ct], 0, 0, 0);
                acc[ct] = __builtin_amdgcn_mfma_f32_16x16x32_bf16(al, bh, acc[ct], 0, 0, 0);
            }
        }
    }

    const int orow = r0 + 16 * w + (lane >> 4) * 4;
    #pragma unroll
    for (int ct = 0; ct < 4; ++ct) {
        const int n = ct * 16 + (lane & 15);
        const float c0n = c0[n];
        #pragma unroll
        for (int j = 0; j < 4; ++j)
            Bu[(size_t)(orow + j) * NS + n] = acc[ct][j] + c0n;
    }
}

// ---- Kernel 2: fused scan + swapped-operand gemmC. Grid 512, 512 thr. ----
// Wave 0 scans 64 rows -> h in XOR-swizzled LDS; waves 1-7 stage gd/bd.
// Then each wave computes acc = mfma(C_frag, h_frag): lane owns out elements
// (row = 16*rg+(lane&15), d = dblk*32+(lane>>4)*8+{0..7}) -> x/out accessed
// as 2x float4 per dblk (16 rows x 128 contiguous B per instruction).
__global__ __launch_bounds__(512, 4) void k_scanC(const float* __restrict__ x,
                                                  const unsigned short* __restrict__ PC2,
                                                  const float* __restrict__ gd,
                                                  const float* __restrict__ bd,
                                                  const float* __restrict__ stats,
                                                  const float* __restrict__ Bu,
                                                  float* __restrict__ out) {
    __shared__ __align__(16) char smem[8192 + 4096];   // h (8K) + gd/bd (4K)
    const int tid = threadIdx.x;
    const int seg = blockIdx.x & (SEGS - 1);
    const int b   = blockIdx.x >> 5;
    const int l0  = seg * LSEG;
    const int rowbase = b * L_ + l0;         // first live row

    if (tid < 64) {
        constexpr int G = 16;
        const int n     = tid;
        const int start = (seg == 0) ? 0 : (l0 - WARM);
        const int skip  = l0 - start;            // 0 or 64
        const int nGrp  = (l0 + LSEG - start) / G;
        const float* bp = Bu + ((size_t)b * L_ + start) * NS + n;
        char* hbase = smem;

        float bufA[G], bufB[G];
        #pragma unroll
        for (int j = 0; j < G; ++j) bufA[j] = KLN * bp[(size_t)j * NS];
        float hv = 0.0f;
        int g = 0;
        for (;;) {
            {
                if (g + 1 < nGrp) {
                    const int base = (g + 1) * G;
                    #pragma unroll
                    for (int j = 0; j < G; ++j)
                        bufB[j] = KLN * bp[(size_t)(base + j) * NS];
                }
                const int lbase = g * G - skip;
                const bool doStore = lbase >= 0;
                #pragma unroll
                for (int j = 0; j < G; ++j) {
                    float t = fmaf(hv, KLN, bufA[j]);
                    float e = __builtin_amdgcn_exp2f(t);
                    float rr = __builtin_amdgcn_rcpf(e + 1.0f);
                    hv = fmaf(-2.0f, rr, 1.0f);
                    if (doStore) {
                        const int lr = lbase + j;
                        *reinterpret_cast<unsigned short*>(
                            hbase + lr * 128 + ((2 * n) ^ ((lr & 7) << 4))) = f2bf(hv);
                    }
                }
            }
            if (++g == nGrp) break;
            {
                if (g + 1 < nGrp) {
                    const int base = (g + 1) * G;
                    #pragma unroll
                    for (int j = 0; j < G; ++j)
                        bufA[j] = KLN * bp[(size_t)(base + j) * NS];
                }
                const int lbase = g * G - skip;
                const bool doStore = lbase >= 0;
                #pragma unroll
                for (int j = 0; j < G; ++j) {
                    float t = fmaf(hv, KLN, bufB[j]);
                    float e = __builtin_amdgcn_exp2f(t);
                    float rr = __builtin_amdgcn_rcpf(e + 1.0f);
                    hv = fmaf(-2.0f, rr, 1.0f);
                    if (doStore) {
                        const int lr = lbase + j;
                        *reinterpret_cast<unsigned short*>(
                            hbase + lr * 128 + ((2 * n) ^ ((lr & 7) << 4))) = f2bf(hv);
                    }
                }
            }
            if (++g == nGrp) break;
        }
    } else {
        float* GdS = (float*)(smem + 8192);
        const int t2 = tid - 64;                 // 0..447
        if (t2 < 256)
            reinterpret_cast<float4*>(GdS)[t2] =
                (t2 < 128) ? reinterpret_cast<const float4*>(gd)[t2]
                           : reinterpret_cast<const float4*>(bd)[t2 - 128];
    }
    __syncthreads();

    // ---- swapped gemmC phase: wave w -> row-group (w&3), d-half (w>>2) ----
    const int w    = tid >> 6;
    const int lane = tid & 63;
    const int rg   = w & 3;
    const int half = w >> 2;
    const int hr   = rg * 16 + (lane & 15);     // local row 0..63
    const int kb   = (lane >> 4) * 8;
    const int grow = rowbase + hr;
    const float mean = stats[2 * grow];
    const float rstd = stats[2 * grow + 1];

    bf16x8 hfr0 = *reinterpret_cast<const bf16x8*>(
        smem + hr * 128 + (((lane >> 4) * 16) ^ ((hr & 7) << 4)));
    bf16x8 hfr1 = *reinterpret_cast<const bf16x8*>(
        smem + hr * 128 + ((64 + (lane >> 4) * 16) ^ ((hr & 7) << 4)));

    const float* GdS = (const float*)(smem + 8192);
    const float* BdS = GdS + DM;
    const float* xrp = x + (size_t)grow * DM;
    float* orp = out + (size_t)grow * DM;

    #pragma unroll
    for (int i = 0; i < 8; ++i) {
        const int dblk = half * 8 + i;
        bf16x8 c00 = *reinterpret_cast<const bf16x8*>(PC2 + ((size_t)dblk * 256 + lane) * 8);
        bf16x8 c01 = *reinterpret_cast<const bf16x8*>(PC2 + ((size_t)dblk * 256 + 64 + lane) * 8);
        bf16x8 c10 = *reinterpret_cast<const bf16x8*>(PC2 + ((size_t)dblk * 256 + 128 + lane) * 8);
        bf16x8 c11 = *reinterpret_cast<const bf16x8*>(PC2 + ((size_t)dblk * 256 + 192 + lane) * 8);
        f32x4 a0 = {}, a1 = {};
        a0 = __builtin_amdgcn_mfma_f32_16x16x32_bf16(c00, hfr0, a0, 0, 0, 0);
        a0 = __builtin_amdgcn_mfma_f32_16x16x32_bf16(c01, hfr1, a0, 0, 0, 0);
        a1 = __builtin_amdgcn_mfma_f32_16x16x32_bf16(c10, hfr0, a1, 0, 0, 0);
        a1 = __builtin_amdgcn_mfma_f32_16x16x32_bf16(c11, hfr1, a1, 0, 0, 0);

        const int db = dblk * 32 + kb;
        const float4 x0 = *reinterpret_cast<const float4*>(xrp + db);
        const float4 x1 = *reinterpret_cast<const float4*>(xrp + db + 4);
        const float4 g0 = *reinterpret_cast<const float4*>(GdS + db);
        const float4 g1 = *reinterpret_cast<const float4*>(GdS + db + 4);
        const float4 d0 = *reinterpret_cast<const float4*>(BdS + db);
        const float4 d1 = *reinterpret_cast<const float4*>(BdS + db + 4);
        float4 o0, o1;
        o0.x = fmaf((x0.x - mean) * rstd, g0.x, a0[0] + d0.x + x0.x);
        o0.y = fmaf((x0.y - mean) * rstd, g0.y, a0[1] + d0.y + x0.y);
        o0.z = fmaf((x0.z - mean) * rstd, g0.z, a0[2] + d0.z + x0.z);
        o0.w = fmaf((x0.w - mean) * rstd, g0.w, a0[3] + d0.w + x0.w);
        o1.x = fmaf((x1.x - mean) * rstd, g1.x, a1[0] + d1.x + x1.x);
        o1.y = fmaf((x1.y - mean) * rstd, g1.y, a1[1] + d1.y + x1.y);
        o1.z = fmaf((x1.z - mean) * rstd, g1.z, a1[2] + d1.z + x1.z);
        o1.w = fmaf((x1.w - mean) * rstd, g1.w, a1[3] + d1.w + x1.w);
        *reinterpret_cast<float4*>(orp + db)     = o0;
        *reinterpret_cast<float4*>(orp + db + 4) = o1;
    }
}

extern "C" void kernel_launch(void* const* d_in, const int* in_sizes, int n_in,
                              void* d_out, int out_size, void* d_ws, size_t ws_size,
                              hipStream_t stream) {
    const float* x     = (const float*)d_in[0];
    const float* A     = (const float*)d_in[1];
    const float* C     = (const float*)d_in[2];
    const float* Dv    = (const float*)d_in[3];
    const float* gamma = (const float*)d_in[4];
    const float* beta  = (const float*)d_in[5];
    float* out = (float*)d_out;

    char* ws = (char*)d_ws;
    float* Bu           = (float*)(ws);                             // 8 MB
    float* stats        = (float*)(ws + (size_t)BL * NS * 4);       // 256 KB
    char* p = ws + (size_t)BL * NS * 4 + (size_t)BL * 2 * 4;
    unsigned short* PAh = (unsigned short*)p;        p += (size_t)DM * NS * 2;
    unsigned short* PAl = (unsigned short*)p;        p += (size_t)DM * NS * 2;
    unsigned short* PC2 = (unsigned short*)p;        p += (size_t)DM * NS * 2;
    float* c0           = (float*)p;                 p += 256;
    float* gd           = (float*)p;                 p += (size_t)DM * 4;
    float* bd           = (float*)p;

    k_pack<<<33, 256, 0, stream>>>(A, C, gamma, beta, Dv, PAh, PAl, PC2, c0, gd, bd);
    k_gemmA<<<BL / 64, 256, 0, stream>>>(x, PAh, PAl, c0, stats, Bu);
    k_scanC<<<B_ * SEGS, 512, 0, stream>>>(x, PC2, gd, bd, stats, Bu, out);
}